// Round 9
// baseline (1627.779 us; speedup 1.0000x reference)
//
#include <hip/hip_runtime.h>
#include <math.h>

// Dims (fixed by the problem)
#define HH   50          // hidden
#define GG   150         // 3H
#define XGS  152         // xg row stride (padded)
#define TTT  2048        // T
#define NB   64          // batch B
#define MTOT (TTT*NB)    // 131072 rows per layer
#define D0   128         // layer-0 input dim

static __device__ __forceinline__ float sigm(float x) {
    return 1.f / (1.f + __expf(-x));
}
static __device__ __forceinline__ float tanh_f(float x) {
    return 1.f - 2.f / (__expf(2.f * x) + 1.f);   // saturates correctly at +/-inf
}

// ---------------- Projection v2: xg = Xin @ W + bi ----------------
// 128 threads (2 waves), tile 128 rows x 64 cols, thread = 8x8 register tile.
// Thread's rows are interleaved (rowg + 16*i) so each xs b128 read has its 8
// row-addresses stride XSP floats with XSP%32 in {4,20} -> all banks spread,
// conflict-free. Per k4: 8 b128 xs + 8 b128 wt feed 256 lane-FMAs (0.5 B/FMA,
// under the 85 B/cyc LDS ceiling -> FMA-bound). L0 runs k in NCH=2 chunks.
template<int KREAL, int KC, int NCH, int XSP, bool L0>
__global__ __launch_bounds__(128) void proj_gemm2(
    const float* __restrict__ Xin,
    const float* __restrict__ W,              // [KREAL,150] f32
    const float* __restrict__ bias,           // [2,150] f32 (bi = bias[0])
    float* __restrict__ xg)                   // [MTOT,XGS] f32
{
    __shared__ __align__(16) float xs[128][XSP];      // L0: 34.8 KB, H: 26.6 KB
    __shared__ __align__(16) float wt[KC][64];        // L0: 16.4 KB, H: 13.3 KB
    const int tid = threadIdx.x;
    const int m0 = blockIdx.x * 128;
    const int c0 = blockIdx.y * 64;
    const int rowg = tid >> 3;                // 0..15
    const int colg = tid & 7;                 // 0..7

    float acc[8][8];
    #pragma unroll
    for (int i = 0; i < 8; ++i)
        #pragma unroll
        for (int c = 0; c < 8; ++c) acc[i][c] = 0.f;

    for (int ch = 0; ch < NCH; ++ch) {
        const int ko = ch * KC;
        if (ch) __syncthreads();              // protect LDS reuse across chunks
        // ---- stage xs ----
        if (L0) {
            for (int i = tid; i < 128 * (KC / 4); i += 128) {
                int r = i / (KC / 4), kq = i % (KC / 4);
                int t = (m0 + r) >> 6, b = (m0 + r) & 63;
                *(float4*)&xs[r][kq * 4] =
                    *(const float4*)(Xin + ((size_t)b * TTT + t) * D0 + ko + kq * 4);
            }
        } else {
            for (int i = tid; i < 128 * KC; i += 128) {
                int r = i / KC, k = i % KC;
                xs[r][k] = (k < KREAL) ? Xin[(size_t)(m0 + r) * KREAL + k] : 0.f;
            }
        }
        // ---- stage wt ----
        for (int i = tid; i < KC * 64; i += 128) {
            int k = i >> 6, c = i & 63;
            wt[k][c] = (ko + k < KREAL && c0 + c < GG) ? W[(size_t)(ko + k) * GG + c0 + c] : 0.f;
        }
        __syncthreads();
        // ---- compute ----
        for (int k4 = 0; k4 < KC; k4 += 4) {
            float xv[8][4];
            #pragma unroll
            for (int i = 0; i < 8; ++i) {
                float4 v = *(const float4*)&xs[rowg + 16 * i][k4];
                xv[i][0] = v.x; xv[i][1] = v.y; xv[i][2] = v.z; xv[i][3] = v.w;
            }
            float wv[4][8];
            #pragma unroll
            for (int j = 0; j < 4; ++j) {
                float4 a = *(const float4*)&wt[k4 + j][colg * 8];
                float4 b = *(const float4*)&wt[k4 + j][colg * 8 + 4];
                wv[j][0] = a.x; wv[j][1] = a.y; wv[j][2] = a.z; wv[j][3] = a.w;
                wv[j][4] = b.x; wv[j][5] = b.y; wv[j][6] = b.z; wv[j][7] = b.w;
            }
            #pragma unroll
            for (int j = 0; j < 4; ++j)
                #pragma unroll
                for (int i = 0; i < 8; ++i)
                    #pragma unroll
                    for (int c = 0; c < 8; ++c)
                        acc[i][c] += xv[i][j] * wv[j][c];
        }
    }
    // ---- epilogue: bias + store ----
    const int cb = c0 + colg * 8;
    float bv[8];
    #pragma unroll
    for (int c = 0; c < 8; ++c) bv[c] = (cb + c < GG) ? bias[cb + c] : 0.f;
    #pragma unroll
    for (int i = 0; i < 8; ++i) {
        const int row = m0 + rowg + 16 * i;
        if (cb + 7 < GG) {
            float4 o0 = make_float4(acc[i][0] + bv[0], acc[i][1] + bv[1],
                                    acc[i][2] + bv[2], acc[i][3] + bv[3]);
            float4 o1 = make_float4(acc[i][4] + bv[4], acc[i][5] + bv[5],
                                    acc[i][6] + bv[6], acc[i][7] + bv[7]);
            *(float4*)&xg[(size_t)row * XGS + cb] = o0;
            *(float4*)&xg[(size_t)row * XGS + cb + 4] = o1;
        } else {
            #pragma unroll
            for (int c = 0; c < 8; ++c)
                if (cb + c < GG)
                    xg[(size_t)row * XGS + cb + c] = acc[i][c] + bv[c];
        }
    }
}

// ---------------- GRU recurrence, barrier-free wave-autonomous ----------------
template<int WPB, int RPW>
__global__ __launch_bounds__(WPB * 64) void gru_wave(
    const float* __restrict__ xg,             // [dn*Nbatch, XGS] f32 (includes bi)
    const float* __restrict__ U,              // [50,150] f32
    const float* __restrict__ bias,           // [2,150] f32 (br = bias+150)
    float* __restrict__ Xout,                 // [MTOT,50] f32 time-major
    int dn, int Nbatch)
{
    constexpr int R   = WPB * RPW;            // rows per block
    constexpr int LPR = 64 / RPW;             // gate lanes per row
    constexpr int NU  = (HH + LPR - 1) / LPR; // gate k values per lane
    __shared__ __align__(16) float Us[HH * XGS];      // 30.4 KB
    __shared__ __align__(16) float brs[XGS];
    __shared__ __align__(16) float hsT[HH][R];        // transposed h
    __shared__ __align__(16) float rc[R][XGS];        // rec result

    const int tid  = threadIdx.x;
    const int wav  = tid >> 6;
    const int lane = tid & 63;

    for (int i = tid; i < HH * XGS; i += WPB * 64) {
        int c = i % XGS;
        Us[i] = (c < GG) ? U[(i / XGS) * GG + c] : 0.f;
    }
    for (int i = tid; i < XGS; i += WPB * 64) brs[i] = (i < GG) ? bias[GG + i] : 0.f;
    for (int i = tid; i < HH * R; i += WPB * 64) ((float*)hsT)[i] = 0.f;
    __syncthreads();                          // the only block-wide barrier

    // rec role: lanes 0..37 own a 4-col group x this wave's RPW rows
    const int cg = lane;
    float4 brv = make_float4(0.f, 0.f, 0.f, 0.f);
    if (cg < 38) brv = *(const float4*)&brs[cg * 4];

    // gate role: lane = gr*LPR + gk handles (row gr, k = gk + LPR*u)
    const int gr = lane / LPR;
    const int gk = lane % LPR;
    const int nrow = blockIdx.x * R + wav * RPW + gr;
    const int jj = nrow >> 6, bb = nrow & 63;
    float hprev[NU];
    #pragma unroll
    for (int u = 0; u < NU; ++u) hprev[u] = 0.f;

    for (int s = 0; s < dn; ++s) {
        // ---- prefetch this step's gate inputs (lands during rec) ----
        float pz[NU], pr[NU], ph[NU];
        {
            const float* g = xg + ((size_t)s * Nbatch + nrow) * XGS;
            #pragma unroll
            for (int u = 0; u < NU; ++u) {
                int k = gk + LPR * u;
                if (k < HH) { pz[u] = g[k]; pr[u] = g[HH + k]; ph[u] = g[2 * HH + k]; }
            }
        }
        // ---- rec = h @ U + br (this wave's RPW rows x 152 cols) ----
        if (cg < 38) {
            float acc[RPW][4];
            #pragma unroll
            for (int j = 0; j < RPW; ++j) {
                acc[j][0] = brv.x; acc[j][1] = brv.y; acc[j][2] = brv.z; acc[j][3] = brv.w;
            }
            #pragma unroll
            for (int k = 0; k < HH; ++k) {
                float4 w = *(const float4*)&Us[k * XGS + cg * 4];
                float wc[4] = {w.x, w.y, w.z, w.w};
                float hj[RPW];
                {
                    float4 h0 = *(const float4*)&hsT[k][wav * RPW];
                    hj[0] = h0.x; hj[1] = h0.y; hj[2] = h0.z; hj[3] = h0.w;
                    if (RPW == 8) {
                        float4 h1 = *(const float4*)&hsT[k][wav * RPW + 4];
                        hj[4] = h1.x; hj[5] = h1.y; hj[6] = h1.z; hj[7] = h1.w;
                    }
                }
                #pragma unroll
                for (int j = 0; j < RPW; ++j)
                    #pragma unroll
                    for (int cidx = 0; cidx < 4; ++cidx) acc[j][cidx] += hj[j] * wc[cidx];
            }
            #pragma unroll
            for (int j = 0; j < RPW; ++j)
                *(float4*)&rc[wav * RPW + j][cg * 4] = *(const float4*)&acc[j][0];
        }
        // ---- gates + state update + permuted global store ----
        const float* rcrow = rc[wav * RPW + gr];
        #pragma unroll
        for (int u = 0; u < NU; ++u) {
            int k = gk + LPR * u;
            if (k < HH) {
                float rcz = rcrow[k];
                float rcr = rcrow[HH + k];
                float rch = rcrow[2 * HH + k];
                float z  = sigm(pz[u] + rcz);
                float rr = sigm(pr[u] + rcr);
                float hh = tanh_f(ph[u] + rr * rch);
                float hn = z * hprev[u] + (1.f - z) * hh;
                hprev[u] = hn;
                hsT[k][wav * RPW + gr] = hn;
                Xout[((size_t)(jj * dn + s) * NB + bb) * HH + k] = hn;
            }
        }
    }
}

// ---------------- dense2 stage 1: partial sums over K-chunks ----------------
__global__ __launch_bounds__(256) void dense2_part(
    const float* __restrict__ X,              // [MTOT,50] f32 final layer (time-major)
    const float* __restrict__ W2,             // [1600,1600] f32
    float* __restrict__ hpart)                // [16,64,1600] f32 partials
{
    __shared__ __align__(16) float fsT[100][64];      // 25.6 KB  feats[f_local][b]
    __shared__ __align__(16) float wt[100][64];       // 25.6 KB  W2[f_local][c_local]
    const int c0 = blockIdx.x * 64;
    const int f0 = blockIdx.y * 100;
    const int tid = threadIdx.x;
    for (int i = tid; i < 100 * 64; i += 256) {
        int fl = i >> 6, b = i & 63;
        int f = f0 + fl;
        int j = f / HH, k = f % HH;           // feats[b, f] = X[2016+j, b, k]
        fsT[fl][b] = X[((size_t)(TTT - 32 + j) * NB + b) * HH + k];
        wt[fl][i & 63] = W2[(size_t)f * 1600 + c0 + (i & 63)];
    }
    __syncthreads();
    const int bg = tid >> 4;                  // 16 groups of 4 batch rows
    const int cq = tid & 15;                  // 16 groups of 4 cols
    float acc[4][4];
    #pragma unroll
    for (int j = 0; j < 4; ++j)
        #pragma unroll
        for (int cidx = 0; cidx < 4; ++cidx) acc[j][cidx] = 0.f;
    for (int fl = 0; fl < 100; ++fl) {
        float4 hb = *(const float4*)&fsT[fl][bg * 4];
        float4 wv = *(const float4*)&wt[fl][cq * 4];
        float hj[4] = {hb.x, hb.y, hb.z, hb.w};
        float wc[4] = {wv.x, wv.y, wv.z, wv.w};
        #pragma unroll
        for (int j = 0; j < 4; ++j)
            #pragma unroll
            for (int cidx = 0; cidx < 4; ++cidx) acc[j][cidx] += hj[j] * wc[cidx];
    }
    #pragma unroll
    for (int j = 0; j < 4; ++j) {
        size_t idx = ((size_t)blockIdx.y * 64 + bg * 4 + j) * 1600 + c0 + cq * 4;
        *(float4*)&hpart[idx] = *(const float4*)&acc[j][0];
    }
}

// ---------------- dense2 stage 2: reduce partials + bias + relu ----------------
__global__ __launch_bounds__(256) void dense2_reduce(
    const float* __restrict__ hpart,          // [16,64,1600]
    const float* __restrict__ b2,             // [1600]
    float* __restrict__ hout)                 // [64,1600]
{
    int i = blockIdx.x * 256 + threadIdx.x;   // 64*1600 total
    int b = i / 1600, c = i % 1600;
    float s = b2[c];
    #pragma unroll
    for (int p = 0; p < 16; ++p) s += hpart[((size_t)p * 64 + b) * 1600 + c];
    hout[(size_t)b * 1600 + c] = s > 0.f ? s : 0.f;
}

// ---------------- Classifier + softmax -> f32 out ----------------
__global__ __launch_bounds__(256) void cls_kernel(
    const float* __restrict__ hin,            // [64,1600] f32
    const float* __restrict__ Wc,             // [1600,41] f32
    const float* __restrict__ bc,             // [41] f32
    float* __restrict__ out)                  // [64,41] f32
{
    __shared__ float hrow[1600];
    __shared__ float part[41][8];
    __shared__ float lg[41];
    __shared__ float red[2];
    const int b = blockIdx.x;
    const int t = threadIdx.x;
    for (int i = t; i < 1600; i += 256) hrow[i] = hin[(size_t)b * 1600 + i];
    __syncthreads();
    const int cl = t % 41, ch = t / 41;       // 6 chunks x 41 classes (246 active)
    if (t < 246) {
        int fbeg = ch * 267;
        int fend = fbeg + 267; if (fend > 1600) fend = 1600;
        float a = 0.f;
        for (int f = fbeg; f < fend; ++f) a += hrow[f] * Wc[f * 41 + cl];
        part[cl][ch] = a;
    }
    __syncthreads();
    if (t < 41) {
        float s = bc[t];
        #pragma unroll
        for (int chh = 0; chh < 6; ++chh) s += part[t][chh];
        lg[t] = s;
    }
    __syncthreads();
    if (t == 0) {
        float mx = lg[0];
        for (int i = 1; i < 41; ++i) mx = fmaxf(mx, lg[i]);
        red[0] = mx;
    }
    __syncthreads();
    if (t < 41) lg[t] = expf(lg[t] - red[0]);
    __syncthreads();
    if (t == 0) {
        float sm = 0.f;
        for (int i = 0; i < 41; ++i) sm += lg[i];
        red[1] = 1.f / sm;
    }
    __syncthreads();
    if (t < 41) out[b * 41 + t] = lg[t] * red[1];
}

extern "C" void kernel_launch(void* const* d_in, const int* in_sizes, int n_in,
                              void* d_out, int out_size, void* d_ws, size_t ws_size,
                              hipStream_t stream)
{
    const float* x   = (const float*)d_in[0];    // [64,2048,128]
    const float* W0  = (const float*)d_in[1];    // [128,150]
    const float* U0  = (const float*)d_in[2];    // [50,150]
    const float* b0  = (const float*)d_in[3];    // [2,150]
    const float* Ws  = (const float*)d_in[4];    // [5,50,150]
    const float* Us  = (const float*)d_in[5];    // [5,50,150]
    const float* bs  = (const float*)d_in[6];    // [5,2,150]
    const float* W2  = (const float*)d_in[7];    // [1600,1600]
    const float* b2  = (const float*)d_in[8];    // [1600]
    const float* Wc  = (const float*)d_in[9];    // [1600,41]
    const float* bc  = (const float*)d_in[10];   // [41]

    float* xg    = (float*)d_ws;                      // MTOT*XGS f32  (79.7 MB)
    float* Xbuf  = xg + (size_t)MTOT * XGS;           // MTOT*50 f32   (26.2 MB)
    float* hbuf  = Xbuf + (size_t)MTOT * HH;          // 64*1600 f32
    float* hpart = xg;                                // 16*64*1600 f32 — xg dead by then

    static const int rates[6] = {32, 64, 128, 256, 512, 1024};

    // layer 0: proj v2 (k in 2 chunks of 64), gru 1-wave blocks
    proj_gemm2<D0, 64, 2, 68, true><<<dim3(MTOT / 128, 3), 128, 0, stream>>>(x, W0, b0, xg);
    gru_wave<1, 4><<<rates[0] * NB / 4, 64, 0, stream>>>(
        xg, U0, b0, Xbuf, TTT / rates[0], rates[0] * NB);

    for (int l = 1; l < 6; ++l) {
        const float* Wl = Ws + (size_t)(l - 1) * HH * GG;
        const float* Ul = Us + (size_t)(l - 1) * HH * GG;
        const float* bl = bs + (size_t)(l - 1) * 2 * GG;
        proj_gemm2<HH, 52, 1, 52, false><<<dim3(MTOT / 128, 3), 128, 0, stream>>>(Xbuf, Wl, bl, xg);
        int rate = rates[l];
        int Nbatch = rate * NB;
        int dn = TTT / rate;
        if (l == 1) {
            gru_wave<2, 4><<<Nbatch / 8, 128, 0, stream>>>(xg, Ul, bl, Xbuf, dn, Nbatch);
        } else {
            gru_wave<4, 8><<<Nbatch / 32, 256, 0, stream>>>(xg, Ul, bl, Xbuf, dn, Nbatch);
        }
    }
    // head
    dense2_part<<<dim3(25, 16), 256, 0, stream>>>(Xbuf, W2, hpart);
    dense2_reduce<<<(64 * 1600) / 256, 256, 0, stream>>>(hpart, b2, hbuf);
    cls_kernel<<<NB, 256, 0, stream>>>(hbuf, Wc, bc, (float*)d_out);
}